// Round 1
// baseline (1687.747 us; speedup 1.0000x reference)
//
#include <hip/hip_runtime.h>
#include <hip/hip_bf16.h>
#include <math.h>

#define N_USERS 50000
#define N_ITEMS 100000
#define N_NODES 150000
#define N_EDGES 2000000
#define EMBED 64
#define N_LAYERS 3
#define BATCH 8192

// ---------------- concat user+item embeddings into emb ----------------
__global__ __launch_bounds__(256) void k_concat(const float4* __restrict__ ue,
                                                const float4* __restrict__ ie,
                                                float4* __restrict__ emb) {
    int idx = blockIdx.x * 256 + threadIdx.x;            // float4 index
    const int TOT = N_NODES * EMBED / 4;                 // 2,400,000
    const int UPART = N_USERS * EMBED / 4;               // 800,000
    if (idx < TOT) {
        emb[idx] = (idx < UPART) ? ue[idx] : ie[idx - UPART];
    }
}

// ---------------- CSR build ----------------
__global__ __launch_bounds__(256) void k_count(const int* __restrict__ rows, int* __restrict__ cnt) {
    int e = blockIdx.x * 256 + threadIdx.x;
    if (e < N_EDGES) atomicAdd(&cnt[rows[e]], 1);
}

// one block, 1024 threads: exclusive scan of cnt[0..N_NODES) -> row_ptr, cursor
__global__ __launch_bounds__(1024) void k_scan(int* __restrict__ cnt /* in: counts (cursor buf) */,
                                               int* __restrict__ row_ptr,
                                               int* __restrict__ cursor) {
    const int CH = (N_NODES + 1023) / 1024;  // 147
    int tid = threadIdx.x;
    int base = tid * CH;
    int partial = 0;
    for (int k = 0; k < CH; k++) {
        int i = base + k;
        if (i < N_NODES) partial += cnt[i];
    }
    __shared__ int s[1024];
    s[tid] = partial;
    __syncthreads();
    // Hillis-Steele inclusive scan
    for (int off = 1; off < 1024; off <<= 1) {
        int v = (tid >= off) ? s[tid - off] : 0;
        __syncthreads();
        s[tid] += v;
        __syncthreads();
    }
    int running = s[tid] - partial;  // exclusive prefix of this chunk
    for (int k = 0; k < CH; k++) {
        int i = base + k;
        if (i < N_NODES) {
            int c = cnt[i];
            row_ptr[i] = running;
            cursor[i]  = running;
            running += c;
        }
    }
    if (tid == 1023) row_ptr[N_NODES] = s[1023];
}

__global__ __launch_bounds__(256) void k_scatter(const int* __restrict__ rows,
                                                 const int* __restrict__ cols,
                                                 const float* __restrict__ vals,
                                                 int* __restrict__ cursor,
                                                 int* __restrict__ cols_s,
                                                 float* __restrict__ vals_s) {
    int e = blockIdx.x * 256 + threadIdx.x;
    if (e < N_EDGES) {
        int r = rows[e];
        int p = atomicAdd(&cursor[r], 1);
        cols_s[p] = cols[e];
        vals_s[p] = vals[e];
    }
}

// ---------------- SpMM: t1e = A @ emb (CSR, one wave per row) ----------------
__global__ __launch_bounds__(256) void k_spmm(const int* __restrict__ row_ptr,
                                              const int* __restrict__ cols_s,
                                              const float* __restrict__ vals_s,
                                              const float* __restrict__ emb,
                                              float* __restrict__ t1e) {
    int wave = threadIdx.x >> 6, lane = threadIdx.x & 63;
    int row = blockIdx.x * 4 + wave;                     // grid = 37500 exact
    int s = row_ptr[row], e = row_ptr[row + 1];
    float acc = 0.f;
    for (int p = s; p < e; p++) {
        int   c = cols_s[p];
        float v = vals_s[p];
        acc += v * emb[c * EMBED + lane];
    }
    t1e[row * EMBED + lane] = acc;
}

// ---------------- fused dense: emb = leaky_relu(t1e@W1^T+b1 + (emb*t1e)@W2^T+b2) ----------------
__global__ __launch_bounds__(256) void k_dense(const float* __restrict__ t1e,
                                               float* __restrict__ emb,
                                               const float* __restrict__ W1,
                                               const float* __restrict__ b1,
                                               const float* __restrict__ W2,
                                               const float* __restrict__ b2) {
    __shared__ float w1s[64 * 65];
    __shared__ float w2s[64 * 65];
    __shared__ float t1s[4][64];
    __shared__ float ps[4][64];
    int tid = threadIdx.x;
    for (int k = tid; k < 4096; k += 256) {
        int r = k >> 6, c = k & 63;
        w1s[r * 65 + c] = W1[k];
        w2s[r * 65 + c] = W2[k];
    }
    __syncthreads();
    int wave = tid >> 6, lane = tid & 63;
    int row = blockIdx.x * 4 + wave;                     // grid = 37500 exact
    float te = t1e[row * EMBED + lane];
    float e0 = emb[row * EMBED + lane];
    t1s[wave][lane] = te;
    ps[wave][lane]  = te * e0;
    float acc1 = b1[lane];
    float acc2 = b2[lane];
#pragma unroll
    for (int k = 0; k < 64; k++) {
        acc1 += t1s[wave][k] * w1s[lane * 65 + k];
        acc2 += ps[wave][k]  * w2s[lane * 65 + k];
    }
    float v = acc1 + acc2;
    v = (v > 0.f) ? v : 0.01f * v;                       // leaky_relu
    emb[row * EMBED + lane] = v;
}

// ---------------- per-layer scoring: accumulate dot products ----------------
template <int NORMALIZE>
__global__ __launch_bounds__(256) void k_score(const float* __restrict__ emb,
                                               const int* __restrict__ u,
                                               const int* __restrict__ ii,
                                               const int* __restrict__ jj,
                                               float* __restrict__ posAcc,
                                               float* __restrict__ negAcc) {
    int wave = threadIdx.x >> 6, lane = threadIdx.x & 63;
    int b = blockIdx.x * 4 + wave;                       // grid = 2048 exact
    int ru = u[b];
    int ri = N_USERS + ii[b];
    int rj = N_USERS + jj[b];
    float eu = emb[ru * EMBED + lane];
    float ep = emb[ri * EMBED + lane];
    float en = emb[rj * EMBED + lane];
    if (NORMALIZE) {
        float su = eu * eu, sp = ep * ep, sn = en * en;
        for (int o = 1; o < 64; o <<= 1) {
            su += __shfl_xor(su, o);
            sp += __shfl_xor(sp, o);
            sn += __shfl_xor(sn, o);
        }
        eu /= fmaxf(sqrtf(su), 1e-12f);
        ep /= fmaxf(sqrtf(sp), 1e-12f);
        en /= fmaxf(sqrtf(sn), 1e-12f);
    }
    float p = eu * ep, n = eu * en;
    for (int o = 1; o < 64; o <<= 1) {
        p += __shfl_xor(p, o);
        n += __shfl_xor(n, o);
    }
    if (lane == 0) {
        posAcc[b] += p;
        negAcc[b] += n;
    }
}

// ---------------- final loss ----------------
__global__ __launch_bounds__(256) void k_loss(const float* __restrict__ pa,
                                              const float* __restrict__ na,
                                              float* __restrict__ out) {
    int b = blockIdx.x * 256 + threadIdx.x;              // grid = 32 exact
    float z = pa[b] - na[b];
    float x = -z;
    float sp = fmaxf(x, 0.f) + log1pf(expf(-fabsf(x)));  // softplus(-z)
    for (int o = 1; o < 64; o <<= 1) sp += __shfl_xor(sp, o);
    __shared__ float s[4];
    int wave = threadIdx.x >> 6, lane = threadIdx.x & 63;
    if (lane == 0) s[wave] = sp;
    __syncthreads();
    if (threadIdx.x == 0) {
        float t = s[0] + s[1] + s[2] + s[3];
        atomicAdd(out, t * (1.f / (float)BATCH));
    }
}

extern "C" void kernel_launch(void* const* d_in, const int* in_sizes, int n_in,
                              void* d_out, int out_size, void* d_ws, size_t ws_size,
                              hipStream_t stream) {
    const float* user_emb = (const float*)d_in[0];
    const float* item_emb = (const float*)d_in[1];
    const float* W1       = (const float*)d_in[2];
    const float* b1       = (const float*)d_in[3];
    const float* W2       = (const float*)d_in[4];
    const float* b2       = (const float*)d_in[5];
    const float* adj_vals = (const float*)d_in[6];
    const int*   adj_rows = (const int*)d_in[7];
    const int*   adj_cols = (const int*)d_in[8];
    const int*   u_idx    = (const int*)d_in[9];
    const int*   i_idx    = (const int*)d_in[10];
    const int*   j_idx    = (const int*)d_in[11];
    float* out = (float*)d_out;

    // workspace layout (bytes)
    char* ws = (char*)d_ws;
    float* emb     = (float*)(ws);                                  // 38,400,000
    float* t1e     = (float*)(ws + 38400000);                       // 38,400,000
    int*   row_ptr = (int*)  (ws + 76800000);                       // 600,064
    int*   cursor  = (int*)  (ws + 77400064);                       // 600,064 (counts, then cursors)
    int*   cols_s  = (int*)  (ws + 78000128);                       // 8,000,000
    float* vals_s  = (float*)(ws + 86000128);                       // 8,000,000
    float* posAcc  = (float*)(ws + 94000128);                       // 32,768
    float* negAcc  = (float*)(ws + 94032896);                       // 32,768

    hipMemsetAsync(cursor, 0, N_NODES * sizeof(int), stream);
    hipMemsetAsync(posAcc, 0, 2 * BATCH * sizeof(float), stream);
    hipMemsetAsync(d_out, 0, sizeof(float), stream);

    // emb = concat(user_emb, item_emb)
    k_concat<<<(N_NODES * EMBED / 4 + 255) / 256, 256, 0, stream>>>(
        (const float4*)user_emb, (const float4*)item_emb, (float4*)emb);

    // CSR build
    k_count<<<(N_EDGES + 255) / 256, 256, 0, stream>>>(adj_rows, cursor);
    k_scan<<<1, 1024, 0, stream>>>(cursor, row_ptr, cursor);
    k_scatter<<<(N_EDGES + 255) / 256, 256, 0, stream>>>(adj_rows, adj_cols, adj_vals,
                                                         cursor, cols_s, vals_s);

    // layer-0 (unnormalized initial emb) scoring
    k_score<0><<<BATCH / 4, 256, 0, stream>>>(emb, u_idx, i_idx, j_idx, posAcc, negAcc);

    for (int l = 0; l < N_LAYERS; l++) {
        k_spmm<<<N_NODES / 4, 256, 0, stream>>>(row_ptr, cols_s, vals_s, emb, t1e);
        k_dense<<<N_NODES / 4, 256, 0, stream>>>(t1e, emb,
                                                 W1 + l * EMBED * EMBED, b1 + l * EMBED,
                                                 W2 + l * EMBED * EMBED, b2 + l * EMBED);
        k_score<1><<<BATCH / 4, 256, 0, stream>>>(emb, u_idx, i_idx, j_idx, posAcc, negAcc);
    }

    k_loss<<<BATCH / 256, 256, 0, stream>>>(posAcc, negAcc, out);
}

// Round 2
// 996.344 us; speedup vs baseline: 1.6939x; 1.6939x over previous
//
#include <hip/hip_runtime.h>
#include <hip/hip_bf16.h>
#include <math.h>

#define N_USERS 50000
#define N_ITEMS 100000
#define N_NODES 150000
#define N_EDGES 2000000
#define EMBED 64
#define N_LAYERS 3
#define BATCH 8192

#define SCAN_CHUNK 1024
#define SCAN_NBLK ((N_NODES + SCAN_CHUNK - 1) / SCAN_CHUNK)  // 147

// ---------------- concat user+item embeddings into emb ----------------
__global__ __launch_bounds__(256) void k_concat(const float4* __restrict__ ue,
                                                const float4* __restrict__ ie,
                                                float4* __restrict__ emb) {
    int idx = blockIdx.x * 256 + threadIdx.x;            // float4 index
    const int TOT = N_NODES * EMBED / 4;                 // 2,400,000
    const int UPART = N_USERS * EMBED / 4;               // 800,000
    if (idx < TOT) {
        emb[idx] = (idx < UPART) ? ue[idx] : ie[idx - UPART];
    }
}

// ---------------- CSR build ----------------
__global__ __launch_bounds__(256) void k_count(const int* __restrict__ rows, int* __restrict__ cnt) {
    int e = (blockIdx.x * 256 + threadIdx.x) * 4;
    if (e + 3 < N_EDGES) {
        int4 r = *(const int4*)&rows[e];
        atomicAdd(&cnt[r.x], 1);
        atomicAdd(&cnt[r.y], 1);
        atomicAdd(&cnt[r.z], 1);
        atomicAdd(&cnt[r.w], 1);
    } else {
        for (int k = 0; k < 4; k++)
            if (e + k < N_EDGES) atomicAdd(&cnt[rows[e + k]], 1);
    }
}

// block partial sums of counts (1024 elements / block)
__global__ __launch_bounds__(256) void k_scan_partial(const int* __restrict__ cnt,
                                                      int* __restrict__ partials) {
    int base = blockIdx.x * SCAN_CHUNK + threadIdx.x * 4;
    int v = 0;
    if (base + 3 < N_NODES) {
        int4 c = *(const int4*)&cnt[base];
        v = c.x + c.y + c.z + c.w;
    } else {
        for (int k = 0; k < 4; k++)
            if (base + k < N_NODES) v += cnt[base + k];
    }
    for (int o = 1; o < 64; o <<= 1) v += __shfl_xor(v, o);
    __shared__ int s[4];
    int wid = threadIdx.x >> 6, lane = threadIdx.x & 63;
    if (lane == 0) s[wid] = v;
    __syncthreads();
    if (threadIdx.x == 0) partials[blockIdx.x] = s[0] + s[1] + s[2] + s[3];
}

// single small block: exclusive scan of the 147 partials
__global__ __launch_bounds__(256) void k_scan_blk(const int* __restrict__ partials,
                                                  int* __restrict__ blkoff) {
    int tid = threadIdx.x;
    int x = (tid < SCAN_NBLK) ? partials[tid] : 0;
    int v = x;
    int lane = tid & 63, wid = tid >> 6;
    for (int o = 1; o < 64; o <<= 1) {
        int t = __shfl_up(v, o);
        if (lane >= o) v += t;
    }
    __shared__ int ws[4];
    if (lane == 63) ws[wid] = v;
    __syncthreads();
    int add = 0;
    for (int w = 0; w < wid; w++) add += ws[w];
    if (tid < SCAN_NBLK) blkoff[tid] = add + v - x;      // exclusive prefix
}

// apply: per-block exclusive scan + block offset -> row_ptr, cursor
__global__ __launch_bounds__(256) void k_scan_apply(const int* __restrict__ cnt,
                                                    const int* __restrict__ blkoff,
                                                    int* __restrict__ row_ptr,
                                                    int* __restrict__ cursor) {
    int tid = threadIdx.x;
    int base = blockIdx.x * SCAN_CHUNK + tid * 4;
    int c0 = 0, c1 = 0, c2 = 0, c3 = 0;
    if (base + 3 < N_NODES) {
        int4 c = *(const int4*)&cnt[base];
        c0 = c.x; c1 = c.y; c2 = c.z; c3 = c.w;
    } else {
        if (base     < N_NODES) c0 = cnt[base];
        if (base + 1 < N_NODES) c1 = cnt[base + 1];
        if (base + 2 < N_NODES) c2 = cnt[base + 2];
        if (base + 3 < N_NODES) c3 = cnt[base + 3];
    }
    int tsum = c0 + c1 + c2 + c3;
    int lane = tid & 63, wid = tid >> 6;
    int v = tsum;
    for (int o = 1; o < 64; o <<= 1) {
        int t = __shfl_up(v, o);
        if (lane >= o) v += t;
    }
    __shared__ int ws[4];
    if (lane == 63) ws[wid] = v;
    __syncthreads();
    int add = blkoff[blockIdx.x];
    for (int w = 0; w < wid; w++) add += ws[w];
    int excl = add + v - tsum;
    int p0 = excl, p1 = p0 + c0, p2 = p1 + c1, p3 = p2 + c2;
    if (base + 3 < N_NODES) {
        int4 rp = make_int4(p0, p1, p2, p3);
        *(int4*)&row_ptr[base] = rp;
        *(int4*)&cursor[base]  = rp;
    } else {
        int ps[4] = {p0, p1, p2, p3};
        for (int k = 0; k < 4; k++)
            if (base + k < N_NODES) { row_ptr[base + k] = ps[k]; cursor[base + k] = ps[k]; }
    }
    if (base < N_NODES && base + 4 >= N_NODES) {
        row_ptr[N_NODES] = p3 + c3;                      // total edge count
    }
}

__global__ __launch_bounds__(256) void k_scatter(const int* __restrict__ rows,
                                                 const int* __restrict__ cols,
                                                 const float* __restrict__ vals,
                                                 int* __restrict__ cursor,
                                                 int* __restrict__ cols_s,
                                                 float* __restrict__ vals_s) {
    int e = (blockIdx.x * 256 + threadIdx.x) * 4;
    if (e + 3 < N_EDGES) {
        int4   r = *(const int4*)&rows[e];
        int4   c = *(const int4*)&cols[e];
        float4 v = *(const float4*)&vals[e];
        int p;
        p = atomicAdd(&cursor[r.x], 1); cols_s[p] = c.x; vals_s[p] = v.x;
        p = atomicAdd(&cursor[r.y], 1); cols_s[p] = c.y; vals_s[p] = v.y;
        p = atomicAdd(&cursor[r.z], 1); cols_s[p] = c.z; vals_s[p] = v.z;
        p = atomicAdd(&cursor[r.w], 1); cols_s[p] = c.w; vals_s[p] = v.w;
    } else {
        for (int k = 0; k < 4; k++) {
            int ee = e + k;
            if (ee < N_EDGES) {
                int r = rows[ee];
                int p = atomicAdd(&cursor[r], 1);
                cols_s[p] = cols[ee];
                vals_s[p] = vals[ee];
            }
        }
    }
}

// ---------------- SpMM: t1e = A @ emb (CSR, wave per row, 4 edge slots) ----------------
__global__ __launch_bounds__(256) void k_spmm(const int* __restrict__ row_ptr,
                                              const int* __restrict__ cols_s,
                                              const float* __restrict__ vals_s,
                                              const float* __restrict__ emb,
                                              float* __restrict__ t1e) {
    int wave = threadIdx.x >> 6, lane = threadIdx.x & 63;
    int row = blockIdx.x * 4 + wave;                     // grid = 37500 exact
    int slot = lane >> 4;                                // 0..3 : edge slot
    int sl   = lane & 15;                                // dims 4*sl .. 4*sl+3
    int s = row_ptr[row], e = row_ptr[row + 1];
    float4 acc = make_float4(0.f, 0.f, 0.f, 0.f);
    for (int p = s + slot; p < e; p += 4) {
        int   c = cols_s[p];
        float v = vals_s[p];
        float4 ev = *(const float4*)&emb[c * EMBED + 4 * sl];
        acc.x += v * ev.x; acc.y += v * ev.y; acc.z += v * ev.z; acc.w += v * ev.w;
    }
    // combine the 4 edge slots (lanes sl, sl+16, sl+32, sl+48)
    acc.x += __shfl_xor(acc.x, 16); acc.y += __shfl_xor(acc.y, 16);
    acc.z += __shfl_xor(acc.z, 16); acc.w += __shfl_xor(acc.w, 16);
    acc.x += __shfl_xor(acc.x, 32); acc.y += __shfl_xor(acc.y, 32);
    acc.z += __shfl_xor(acc.z, 32); acc.w += __shfl_xor(acc.w, 32);
    if (slot == 0) *(float4*)&t1e[row * EMBED + 4 * sl] = acc;
}

// ---------------- fused dense: emb = leaky_relu(t1e@W1^T+b1 + (emb*t1e)@W2^T+b2) ----------------
__global__ __launch_bounds__(256) void k_dense(const float* __restrict__ t1e,
                                               float* __restrict__ emb,
                                               const float* __restrict__ W1,
                                               const float* __restrict__ b1,
                                               const float* __restrict__ W2,
                                               const float* __restrict__ b2) {
    __shared__ float w1s[64 * 65];
    __shared__ float w2s[64 * 65];
    __shared__ float t1s[4][64];
    __shared__ float ps[4][64];
    int tid = threadIdx.x;
    for (int k = tid; k < 4096; k += 256) {
        int r = k >> 6, c = k & 63;
        w1s[r * 65 + c] = W1[k];
        w2s[r * 65 + c] = W2[k];
    }
    __syncthreads();
    int wave = tid >> 6, lane = tid & 63;
    int row = blockIdx.x * 4 + wave;                     // grid = 37500 exact
    float te = t1e[row * EMBED + lane];
    float e0 = emb[row * EMBED + lane];
    t1s[wave][lane] = te;
    ps[wave][lane]  = te * e0;
    float acc1 = b1[lane];
    float acc2 = b2[lane];
    __syncthreads();
#pragma unroll
    for (int k = 0; k < 64; k++) {
        acc1 += t1s[wave][k] * w1s[lane * 65 + k];
        acc2 += ps[wave][k]  * w2s[lane * 65 + k];
    }
    float v = acc1 + acc2;
    v = (v > 0.f) ? v : 0.01f * v;                       // leaky_relu
    emb[row * EMBED + lane] = v;
}

// ---------------- per-layer scoring: accumulate dot products ----------------
template <int NORMALIZE>
__global__ __launch_bounds__(256) void k_score(const float* __restrict__ emb,
                                               const int* __restrict__ u,
                                               const int* __restrict__ ii,
                                               const int* __restrict__ jj,
                                               float* __restrict__ posAcc,
                                               float* __restrict__ negAcc) {
    int wave = threadIdx.x >> 6, lane = threadIdx.x & 63;
    int b = blockIdx.x * 4 + wave;                       // grid = 2048 exact
    int ru = u[b];
    int ri = N_USERS + ii[b];
    int rj = N_USERS + jj[b];
    float eu = emb[ru * EMBED + lane];
    float ep = emb[ri * EMBED + lane];
    float en = emb[rj * EMBED + lane];
    if (NORMALIZE) {
        float su = eu * eu, sp = ep * ep, sn = en * en;
        for (int o = 1; o < 64; o <<= 1) {
            su += __shfl_xor(su, o);
            sp += __shfl_xor(sp, o);
            sn += __shfl_xor(sn, o);
        }
        eu /= fmaxf(sqrtf(su), 1e-12f);
        ep /= fmaxf(sqrtf(sp), 1e-12f);
        en /= fmaxf(sqrtf(sn), 1e-12f);
    }
    float p = eu * ep, n = eu * en;
    for (int o = 1; o < 64; o <<= 1) {
        p += __shfl_xor(p, o);
        n += __shfl_xor(n, o);
    }
    if (lane == 0) {
        posAcc[b] += p;
        negAcc[b] += n;
    }
}

// ---------------- final loss ----------------
__global__ __launch_bounds__(256) void k_loss(const float* __restrict__ pa,
                                              const float* __restrict__ na,
                                              float* __restrict__ out) {
    int b = blockIdx.x * 256 + threadIdx.x;              // grid = 32 exact
    float z = pa[b] - na[b];
    float x = -z;
    float sp = fmaxf(x, 0.f) + log1pf(expf(-fabsf(x)));  // softplus(-z)
    for (int o = 1; o < 64; o <<= 1) sp += __shfl_xor(sp, o);
    __shared__ float s[4];
    int wave = threadIdx.x >> 6, lane = threadIdx.x & 63;
    if (lane == 0) s[wave] = sp;
    __syncthreads();
    if (threadIdx.x == 0) {
        float t = s[0] + s[1] + s[2] + s[3];
        atomicAdd(out, t * (1.f / (float)BATCH));
    }
}

extern "C" void kernel_launch(void* const* d_in, const int* in_sizes, int n_in,
                              void* d_out, int out_size, void* d_ws, size_t ws_size,
                              hipStream_t stream) {
    const float* user_emb = (const float*)d_in[0];
    const float* item_emb = (const float*)d_in[1];
    const float* W1       = (const float*)d_in[2];
    const float* b1       = (const float*)d_in[3];
    const float* W2       = (const float*)d_in[4];
    const float* b2       = (const float*)d_in[5];
    const float* adj_vals = (const float*)d_in[6];
    const int*   adj_rows = (const int*)d_in[7];
    const int*   adj_cols = (const int*)d_in[8];
    const int*   u_idx    = (const int*)d_in[9];
    const int*   i_idx    = (const int*)d_in[10];
    const int*   j_idx    = (const int*)d_in[11];
    float* out = (float*)d_out;

    // workspace layout (bytes) — same footprint as R1 (<= 94,065,664 B)
    char* ws = (char*)d_ws;
    float* emb     = (float*)(ws);                                  // 38,400,000
    float* t1e     = (float*)(ws + 38400000);                       // 38,400,000
    int*   row_ptr = (int*)  (ws + 76800000);                       // 600,064
    int*   cursor  = (int*)  (ws + 77400064);                       // 600,064 (counts, then cursors)
    int*   cols_s  = (int*)  (ws + 78000128);                       // 8,000,000
    float* vals_s  = (float*)(ws + 86000128);                       // 8,000,000
    float* posAcc  = (float*)(ws + 94000128);                       // 32,768
    float* negAcc  = (float*)(ws + 94032896);                       // 32,768
    // scan scratch lives in the (still unused) t1e region
    int*   partials = (int*)(ws + 38400000);
    int*   blkoff   = (int*)(ws + 38400000 + 4096);

    hipMemsetAsync(cursor, 0, N_NODES * sizeof(int), stream);
    hipMemsetAsync(posAcc, 0, 2 * BATCH * sizeof(float), stream);
    hipMemsetAsync(d_out, 0, sizeof(float), stream);

    // emb = concat(user_emb, item_emb)
    k_concat<<<(N_NODES * EMBED / 4 + 255) / 256, 256, 0, stream>>>(
        (const float4*)user_emb, (const float4*)item_emb, (float4*)emb);

    // CSR build (hierarchical scan)
    k_count<<<(N_EDGES / 4 + 255) / 256, 256, 0, stream>>>(adj_rows, cursor);
    k_scan_partial<<<SCAN_NBLK, 256, 0, stream>>>(cursor, partials);
    k_scan_blk<<<1, 256, 0, stream>>>(partials, blkoff);
    k_scan_apply<<<SCAN_NBLK, 256, 0, stream>>>(cursor, blkoff, row_ptr, cursor);
    k_scatter<<<(N_EDGES / 4 + 255) / 256, 256, 0, stream>>>(adj_rows, adj_cols, adj_vals,
                                                             cursor, cols_s, vals_s);

    // layer-0 (unnormalized initial emb) scoring
    k_score<0><<<BATCH / 4, 256, 0, stream>>>(emb, u_idx, i_idx, j_idx, posAcc, negAcc);

    for (int l = 0; l < N_LAYERS; l++) {
        k_spmm<<<N_NODES / 4, 256, 0, stream>>>(row_ptr, cols_s, vals_s, emb, t1e);
        k_dense<<<N_NODES / 4, 256, 0, stream>>>(t1e, emb,
                                                 W1 + l * EMBED * EMBED, b1 + l * EMBED,
                                                 W2 + l * EMBED * EMBED, b2 + l * EMBED);
        k_score<1><<<BATCH / 4, 256, 0, stream>>>(emb, u_idx, i_idx, j_idx, posAcc, negAcc);
    }

    k_loss<<<BATCH / 256, 256, 0, stream>>>(posAcc, negAcc, out);
}

// Round 3
// 644.406 us; speedup vs baseline: 2.6191x; 1.5461x over previous
//
#include <hip/hip_runtime.h>
#include <hip/hip_bf16.h>
#include <math.h>

#define N_USERS 50000
#define N_ITEMS 100000
#define N_NODES 150000
#define N_EDGES 2000000
#define EMBED 64
#define N_LAYERS 3
#define BATCH 8192

#define SCAN_CHUNK 1024
#define SCAN_NBLK ((N_NODES + SCAN_CHUNK - 1) / SCAN_CHUNK)  // 147

// ---------------- concat user+item embeddings into emb ----------------
__global__ __launch_bounds__(256) void k_concat(const float4* __restrict__ ue,
                                                const float4* __restrict__ ie,
                                                float4* __restrict__ emb) {
    int idx = blockIdx.x * 256 + threadIdx.x;            // float4 index
    const int TOT = N_NODES * EMBED / 4;                 // 2,400,000
    const int UPART = N_USERS * EMBED / 4;               // 800,000
    if (idx < TOT) {
        emb[idx] = (idx < UPART) ? ue[idx] : ie[idx - UPART];
    }
}

// ---------------- CSR build ----------------
__global__ __launch_bounds__(256) void k_count(const int* __restrict__ rows, int* __restrict__ cnt) {
    int e = (blockIdx.x * 256 + threadIdx.x) * 4;
    if (e + 3 < N_EDGES) {
        int4 r = *(const int4*)&rows[e];
        atomicAdd(&cnt[r.x], 1);
        atomicAdd(&cnt[r.y], 1);
        atomicAdd(&cnt[r.z], 1);
        atomicAdd(&cnt[r.w], 1);
    } else {
        for (int k = 0; k < 4; k++)
            if (e + k < N_EDGES) atomicAdd(&cnt[rows[e + k]], 1);
    }
}

// block partial sums of counts (1024 elements / block)
__global__ __launch_bounds__(256) void k_scan_partial(const int* __restrict__ cnt,
                                                      int* __restrict__ partials) {
    int base = blockIdx.x * SCAN_CHUNK + threadIdx.x * 4;
    int v = 0;
    if (base + 3 < N_NODES) {
        int4 c = *(const int4*)&cnt[base];
        v = c.x + c.y + c.z + c.w;
    } else {
        for (int k = 0; k < 4; k++)
            if (base + k < N_NODES) v += cnt[base + k];
    }
    for (int o = 1; o < 64; o <<= 1) v += __shfl_xor(v, o);
    __shared__ int s[4];
    int wid = threadIdx.x >> 6, lane = threadIdx.x & 63;
    if (lane == 0) s[wid] = v;
    __syncthreads();
    if (threadIdx.x == 0) partials[blockIdx.x] = s[0] + s[1] + s[2] + s[3];
}

// single small block: exclusive scan of the 147 partials
__global__ __launch_bounds__(256) void k_scan_blk(const int* __restrict__ partials,
                                                  int* __restrict__ blkoff) {
    int tid = threadIdx.x;
    int x = (tid < SCAN_NBLK) ? partials[tid] : 0;
    int v = x;
    int lane = tid & 63, wid = tid >> 6;
    for (int o = 1; o < 64; o <<= 1) {
        int t = __shfl_up(v, o);
        if (lane >= o) v += t;
    }
    __shared__ int ws[4];
    if (lane == 63) ws[wid] = v;
    __syncthreads();
    int add = 0;
    for (int w = 0; w < wid; w++) add += ws[w];
    if (tid < SCAN_NBLK) blkoff[tid] = add + v - x;      // exclusive prefix
}

// apply: per-block exclusive scan + block offset -> row_ptr, cursor
__global__ __launch_bounds__(256) void k_scan_apply(const int* __restrict__ cnt,
                                                    const int* __restrict__ blkoff,
                                                    int* __restrict__ row_ptr,
                                                    int* __restrict__ cursor) {
    int tid = threadIdx.x;
    int base = blockIdx.x * SCAN_CHUNK + tid * 4;
    int c0 = 0, c1 = 0, c2 = 0, c3 = 0;
    if (base + 3 < N_NODES) {
        int4 c = *(const int4*)&cnt[base];
        c0 = c.x; c1 = c.y; c2 = c.z; c3 = c.w;
    } else {
        if (base     < N_NODES) c0 = cnt[base];
        if (base + 1 < N_NODES) c1 = cnt[base + 1];
        if (base + 2 < N_NODES) c2 = cnt[base + 2];
        if (base + 3 < N_NODES) c3 = cnt[base + 3];
    }
    int tsum = c0 + c1 + c2 + c3;
    int lane = tid & 63, wid = tid >> 6;
    int v = tsum;
    for (int o = 1; o < 64; o <<= 1) {
        int t = __shfl_up(v, o);
        if (lane >= o) v += t;
    }
    __shared__ int ws[4];
    if (lane == 63) ws[wid] = v;
    __syncthreads();
    int add = blkoff[blockIdx.x];
    for (int w = 0; w < wid; w++) add += ws[w];
    int excl = add + v - tsum;
    int p0 = excl, p1 = p0 + c0, p2 = p1 + c1, p3 = p2 + c2;
    if (base + 3 < N_NODES) {
        int4 rp = make_int4(p0, p1, p2, p3);
        *(int4*)&row_ptr[base] = rp;
        *(int4*)&cursor[base]  = rp;
    } else {
        int ps[4] = {p0, p1, p2, p3};
        for (int k = 0; k < 4; k++)
            if (base + k < N_NODES) { row_ptr[base + k] = ps[k]; cursor[base + k] = ps[k]; }
    }
    if (base < N_NODES && base + 4 >= N_NODES) {
        row_ptr[N_NODES] = p3 + c3;                      // total edge count
    }
}

__global__ __launch_bounds__(256) void k_scatter(const int* __restrict__ rows,
                                                 const int* __restrict__ cols,
                                                 const float* __restrict__ vals,
                                                 int* __restrict__ cursor,
                                                 int* __restrict__ cols_s,
                                                 float* __restrict__ vals_s) {
    int e = (blockIdx.x * 256 + threadIdx.x) * 4;
    if (e + 3 < N_EDGES) {
        int4   r = *(const int4*)&rows[e];
        int4   c = *(const int4*)&cols[e];
        float4 v = *(const float4*)&vals[e];
        int p;
        p = atomicAdd(&cursor[r.x], 1); cols_s[p] = c.x; vals_s[p] = v.x;
        p = atomicAdd(&cursor[r.y], 1); cols_s[p] = c.y; vals_s[p] = v.y;
        p = atomicAdd(&cursor[r.z], 1); cols_s[p] = c.z; vals_s[p] = v.z;
        p = atomicAdd(&cursor[r.w], 1); cols_s[p] = c.w; vals_s[p] = v.w;
    } else {
        for (int k = 0; k < 4; k++) {
            int ee = e + k;
            if (ee < N_EDGES) {
                int r = rows[ee];
                int p = atomicAdd(&cursor[r], 1);
                cols_s[p] = cols[ee];
                vals_s[p] = vals[ee];
            }
        }
    }
}

// ---------------- SpMM: t1e = A @ emb (CSR, wave per row, 4 edge slots) ----------------
__global__ __launch_bounds__(256) void k_spmm(const int* __restrict__ row_ptr,
                                              const int* __restrict__ cols_s,
                                              const float* __restrict__ vals_s,
                                              const float* __restrict__ emb,
                                              float* __restrict__ t1e) {
    int wave = threadIdx.x >> 6, lane = threadIdx.x & 63;
    int row = blockIdx.x * 4 + wave;                     // grid = 37500 exact
    int slot = lane >> 4;                                // 0..3 : edge slot
    int sl   = lane & 15;                                // dims 4*sl .. 4*sl+3
    int s = row_ptr[row], e = row_ptr[row + 1];
    float4 acc = make_float4(0.f, 0.f, 0.f, 0.f);
    for (int p = s + slot; p < e; p += 4) {
        int   c = cols_s[p];
        float v = vals_s[p];
        float4 ev = *(const float4*)&emb[c * EMBED + 4 * sl];
        acc.x += v * ev.x; acc.y += v * ev.y; acc.z += v * ev.z; acc.w += v * ev.w;
    }
    // combine the 4 edge slots (lanes sl, sl+16, sl+32, sl+48)
    acc.x += __shfl_xor(acc.x, 16); acc.y += __shfl_xor(acc.y, 16);
    acc.z += __shfl_xor(acc.z, 16); acc.w += __shfl_xor(acc.w, 16);
    acc.x += __shfl_xor(acc.x, 32); acc.y += __shfl_xor(acc.y, 32);
    acc.z += __shfl_xor(acc.z, 32); acc.w += __shfl_xor(acc.w, 32);
    if (slot == 0) *(float4*)&t1e[row * EMBED + 4 * sl] = acc;
}

// ---------------- fused dense: emb = leaky_relu(t1e@W1^T+b1 + (emb*t1e)@W2^T+b2) ----------------
// Register-tiled GEMM: block = 256 threads, M-tile 64, K = 64, 4x4 outputs/thread.
// LDS holds transposed tiles [k][m] / [k][n], stride 68 (float4-aligned, conflict-free).
__global__ __launch_bounds__(256) void k_dense(const float* __restrict__ t1e,
                                               float* __restrict__ emb,
                                               const float* __restrict__ W1,
                                               const float* __restrict__ b1,
                                               const float* __restrict__ W2,
                                               const float* __restrict__ b2) {
    __shared__ float A1s[64][68];   // [k][m] = t1e[row0+m][k]
    __shared__ float A2s[64][68];   // [k][m] = emb[row0+m][k] * t1e[row0+m][k]
    __shared__ float B1s[64][68];   // [k][n] = W1[n][k]
    __shared__ float B2s[64][68];   // [k][n] = W2[n][k]
    __shared__ float bs[64];        // b1[n] + b2[n]

    int tid  = threadIdx.x;
    int row0 = blockIdx.x * 64;

    // --- fill B tiles (transpose W1/W2) + bias ---
    {
        int f0 = tid * 16;                               // 4096 floats / 256 threads
#pragma unroll
        for (int q = 0; q < 4; q++) {
            int f = f0 + q * 4;
            int n = f >> 6, k = f & 63;
            float4 w1 = *(const float4*)&W1[f];
            float4 w2 = *(const float4*)&W2[f];
            B1s[k + 0][n] = w1.x; B1s[k + 1][n] = w1.y; B1s[k + 2][n] = w1.z; B1s[k + 3][n] = w1.w;
            B2s[k + 0][n] = w2.x; B2s[k + 1][n] = w2.y; B2s[k + 2][n] = w2.z; B2s[k + 3][n] = w2.w;
        }
        if (tid < 64) bs[tid] = b1[tid] + b2[tid];
    }

    // --- fill A tiles (transpose t1e / emb*t1e rows) ---
    {
        int r   = tid >> 2;                              // 0..63
        int row = row0 + r;
        bool ok = row < N_NODES;
#pragma unroll
        for (int q = 0; q < 4; q++) {
            int c = ((tid & 3) * 4 + q) * 4;             // k base
            float4 t = make_float4(0.f, 0.f, 0.f, 0.f);
            float4 e = make_float4(0.f, 0.f, 0.f, 0.f);
            if (ok) {
                t = *(const float4*)&t1e[row * EMBED + c];
                e = *(const float4*)&emb[row * EMBED + c];
            }
            A1s[c + 0][r] = t.x;       A1s[c + 1][r] = t.y;
            A1s[c + 2][r] = t.z;       A1s[c + 3][r] = t.w;
            A2s[c + 0][r] = t.x * e.x; A2s[c + 1][r] = t.y * e.y;
            A2s[c + 2][r] = t.z * e.z; A2s[c + 3][r] = t.w * e.w;
        }
    }
    __syncthreads();

    int tr = tid >> 4, tc = tid & 15;
    int m0 = tr * 4, n0 = tc * 4;
    float acc[4][4] = {};

#pragma unroll 8
    for (int k = 0; k < 64; k++) {
        float4 a1v = *(const float4*)&A1s[k][m0];
        float4 a2v = *(const float4*)&A2s[k][m0];
        float4 b1v = *(const float4*)&B1s[k][n0];
        float4 b2v = *(const float4*)&B2s[k][n0];
        float a1[4] = {a1v.x, a1v.y, a1v.z, a1v.w};
        float a2[4] = {a2v.x, a2v.y, a2v.z, a2v.w};
        float bb1[4] = {b1v.x, b1v.y, b1v.z, b1v.w};
        float bb2[4] = {b2v.x, b2v.y, b2v.z, b2v.w};
#pragma unroll
        for (int i = 0; i < 4; i++)
#pragma unroll
            for (int j = 0; j < 4; j++)
                acc[i][j] += a1[i] * bb1[j] + a2[i] * bb2[j];
    }

    // --- epilogue: bias + leaky relu + store ---
    float bias[4] = {bs[n0], bs[n0 + 1], bs[n0 + 2], bs[n0 + 3]};
#pragma unroll
    for (int i = 0; i < 4; i++) {
        int row = row0 + m0 + i;
        if (row < N_NODES) {
            float o[4];
#pragma unroll
            for (int j = 0; j < 4; j++) {
                float v = acc[i][j] + bias[j];
                o[j] = (v > 0.f) ? v : 0.01f * v;
            }
            float4 ov = make_float4(o[0], o[1], o[2], o[3]);
            *(float4*)&emb[row * EMBED + n0] = ov;
        }
    }
}

// ---------------- per-layer scoring: accumulate dot products ----------------
template <int NORMALIZE>
__global__ __launch_bounds__(256) void k_score(const float* __restrict__ emb,
                                               const int* __restrict__ u,
                                               const int* __restrict__ ii,
                                               const int* __restrict__ jj,
                                               float* __restrict__ posAcc,
                                               float* __restrict__ negAcc) {
    int wave = threadIdx.x >> 6, lane = threadIdx.x & 63;
    int b = blockIdx.x * 4 + wave;                       // grid = 2048 exact
    int ru = u[b];
    int ri = N_USERS + ii[b];
    int rj = N_USERS + jj[b];
    float eu = emb[ru * EMBED + lane];
    float ep = emb[ri * EMBED + lane];
    float en = emb[rj * EMBED + lane];
    if (NORMALIZE) {
        float su = eu * eu, sp = ep * ep, sn = en * en;
        for (int o = 1; o < 64; o <<= 1) {
            su += __shfl_xor(su, o);
            sp += __shfl_xor(sp, o);
            sn += __shfl_xor(sn, o);
        }
        eu /= fmaxf(sqrtf(su), 1e-12f);
        ep /= fmaxf(sqrtf(sp), 1e-12f);
        en /= fmaxf(sqrtf(sn), 1e-12f);
    }
    float p = eu * ep, n = eu * en;
    for (int o = 1; o < 64; o <<= 1) {
        p += __shfl_xor(p, o);
        n += __shfl_xor(n, o);
    }
    if (lane == 0) {
        posAcc[b] += p;
        negAcc[b] += n;
    }
}

// ---------------- final loss ----------------
__global__ __launch_bounds__(256) void k_loss(const float* __restrict__ pa,
                                              const float* __restrict__ na,
                                              float* __restrict__ out) {
    int b = blockIdx.x * 256 + threadIdx.x;              // grid = 32 exact
    float z = pa[b] - na[b];
    float x = -z;
    float sp = fmaxf(x, 0.f) + log1pf(expf(-fabsf(x)));  // softplus(-z)
    for (int o = 1; o < 64; o <<= 1) sp += __shfl_xor(sp, o);
    __shared__ float s[4];
    int wave = threadIdx.x >> 6, lane = threadIdx.x & 63;
    if (lane == 0) s[wave] = sp;
    __syncthreads();
    if (threadIdx.x == 0) {
        float t = s[0] + s[1] + s[2] + s[3];
        atomicAdd(out, t * (1.f / (float)BATCH));
    }
}

extern "C" void kernel_launch(void* const* d_in, const int* in_sizes, int n_in,
                              void* d_out, int out_size, void* d_ws, size_t ws_size,
                              hipStream_t stream) {
    const float* user_emb = (const float*)d_in[0];
    const float* item_emb = (const float*)d_in[1];
    const float* W1       = (const float*)d_in[2];
    const float* b1       = (const float*)d_in[3];
    const float* W2       = (const float*)d_in[4];
    const float* b2       = (const float*)d_in[5];
    const float* adj_vals = (const float*)d_in[6];
    const int*   adj_rows = (const int*)d_in[7];
    const int*   adj_cols = (const int*)d_in[8];
    const int*   u_idx    = (const int*)d_in[9];
    const int*   i_idx    = (const int*)d_in[10];
    const int*   j_idx    = (const int*)d_in[11];
    float* out = (float*)d_out;

    // workspace layout (bytes) — <= 94,065,664 B
    char* ws = (char*)d_ws;
    float* emb     = (float*)(ws);                                  // 38,400,000
    float* t1e     = (float*)(ws + 38400000);                       // 38,400,000
    int*   row_ptr = (int*)  (ws + 76800000);                       // 600,064
    int*   cursor  = (int*)  (ws + 77400064);                       // 600,064 (counts, then cursors)
    int*   cols_s  = (int*)  (ws + 78000128);                       // 8,000,000
    float* vals_s  = (float*)(ws + 86000128);                       // 8,000,000
    float* posAcc  = (float*)(ws + 94000128);                       // 32,768
    float* negAcc  = (float*)(ws + 94032896);                       // 32,768
    // scan scratch lives in the (still unused) t1e region
    int*   partials = (int*)(ws + 38400000);
    int*   blkoff   = (int*)(ws + 38400000 + 4096);

    hipMemsetAsync(cursor, 0, N_NODES * sizeof(int), stream);
    hipMemsetAsync(posAcc, 0, 2 * BATCH * sizeof(float), stream);
    hipMemsetAsync(d_out, 0, sizeof(float), stream);

    // emb = concat(user_emb, item_emb)
    k_concat<<<(N_NODES * EMBED / 4 + 255) / 256, 256, 0, stream>>>(
        (const float4*)user_emb, (const float4*)item_emb, (float4*)emb);

    // CSR build (hierarchical scan)
    k_count<<<(N_EDGES / 4 + 255) / 256, 256, 0, stream>>>(adj_rows, cursor);
    k_scan_partial<<<SCAN_NBLK, 256, 0, stream>>>(cursor, partials);
    k_scan_blk<<<1, 256, 0, stream>>>(partials, blkoff);
    k_scan_apply<<<SCAN_NBLK, 256, 0, stream>>>(cursor, blkoff, row_ptr, cursor);
    k_scatter<<<(N_EDGES / 4 + 255) / 256, 256, 0, stream>>>(adj_rows, adj_cols, adj_vals,
                                                             cursor, cols_s, vals_s);

    // layer-0 (unnormalized initial emb) scoring
    k_score<0><<<BATCH / 4, 256, 0, stream>>>(emb, u_idx, i_idx, j_idx, posAcc, negAcc);

    for (int l = 0; l < N_LAYERS; l++) {
        k_spmm<<<N_NODES / 4, 256, 0, stream>>>(row_ptr, cols_s, vals_s, emb, t1e);
        k_dense<<<(N_NODES + 63) / 64, 256, 0, stream>>>(t1e, emb,
                                                 W1 + l * EMBED * EMBED, b1 + l * EMBED,
                                                 W2 + l * EMBED * EMBED, b2 + l * EMBED);
        k_score<1><<<BATCH / 4, 256, 0, stream>>>(emb, u_idx, i_idx, j_idx, posAcc, negAcc);
    }

    k_loss<<<BATCH / 256, 256, 0, stream>>>(posAcc, negAcc, out);
}